// Round 12
// baseline (207.127 us; speedup 1.0000x reference)
//
#include <hip/hip_runtime.h>

#define DM 1024
#define NH 16
#define HD 64
#define SEQ 2048
#define BATCH 4
#define MROWS (BATCH*SEQ)   // 8192

typedef short short8 __attribute__((ext_vector_type(8)));
typedef float f32x4 __attribute__((ext_vector_type(4)));
typedef unsigned short u16x8 __attribute__((ext_vector_type(8)));
typedef unsigned short u16x4 __attribute__((ext_vector_type(4)));

__device__ inline unsigned short f2b(float f) {
    union { float f; unsigned u; } v; v.f = f;
    unsigned r = v.u + 0x7fffu + ((v.u >> 16) & 1u);   // RNE
    return (unsigned short)(r >> 16);
}

__device__ inline void gload_lds16(const void* g, void* l) {
    __builtin_amdgcn_global_load_lds(
        (const __attribute__((address_space(1))) void*)g,
        (__attribute__((address_space(3))) void*)l, 16, 0, 0);
}

__device__ inline unsigned cvt_pk_bf16(float lo, float hi) {
    unsigned r;
    asm("v_cvt_pk_bf16_f32 %0, %1, %2" : "=v"(r) : "v"(lo), "v"(hi));
    return r;
}

// ---------------- convert x (fp32 -> bf16) ----------------
__global__ void k_cvt_x(const float* __restrict__ x, unsigned short* __restrict__ xb) {
    long i = ((long)blockIdx.x * 256 + threadIdx.x) * 8;
    float4 a = *reinterpret_cast<const float4*>(x + i);
    float4 b = *reinterpret_cast<const float4*>(x + i + 4);
    u16x8 o;
    o[0]=f2b(a.x); o[1]=f2b(a.y); o[2]=f2b(a.z); o[3]=f2b(a.w);
    o[4]=f2b(b.x); o[5]=f2b(b.y); o[6]=f2b(b.z); o[7]=f2b(b.w);
    *reinterpret_cast<u16x8*>(xb + i) = o;
}

// ---------------- convert + transpose W (fp32 [k][n] -> bf16 [n][k]) ----------------
__global__ void k_cvt_wT(const float* W0, const float* W1, const float* W2, const float* W3,
                         unsigned short* __restrict__ out) {
    const float* Ws[4] = {W0, W1, W2, W3};
    const float* W = Ws[blockIdx.z];
    unsigned short* o = out + (size_t)blockIdx.z * DM * DM;
    __shared__ float t[64][65];
    int tx = threadIdx.x & 15, ty = threadIdx.x >> 4;
    int nb = blockIdx.x * 64, kb = blockIdx.y * 64;
#pragma unroll
    for (int i = 0; i < 4; ++i) {
        int r = ty + 16 * i;
        float4 v = *reinterpret_cast<const float4*>(W + (size_t)(kb + r) * DM + nb + tx * 4);
        t[r][tx*4+0] = v.x; t[r][tx*4+1] = v.y; t[r][tx*4+2] = v.z; t[r][tx*4+3] = v.w;
    }
    __syncthreads();
#pragma unroll
    for (int i = 0; i < 4; ++i) {
        int r = ty + 16 * i;                  // n-local
        u16x4 pv;
#pragma unroll
        for (int j = 0; j < 4; ++j) pv[j] = f2b(t[tx*4+j][r]);
        *reinterpret_cast<u16x4*>(o + (size_t)(nb + r) * DM + kb + tx * 4) = pv;
    }
}

#define BM 128
#define BN 128
#define BK 64
#define QSCALE 0.1803368801f   // 0.125 * log2(e)

// ---------------- legacy 128x128 GEMM (used for V only: mode 2) ----------------
__global__ __launch_bounds__(256) void k_gemm(const unsigned short* __restrict__ A,
                                              const unsigned short* __restrict__ Bt,
                                              const float* __restrict__ bias,
                                              unsigned short* __restrict__ outb,
                                              float* __restrict__ outf, int mode) {
    __shared__ unsigned short lds[BM*BK + BN*BK];   // 32 KB
    unsigned short* lA = lds;
    unsigned short* lB = lds + BM*BK;
    int tid = threadIdx.x, lane = tid & 63, wv = tid >> 6;
    int wr = wv >> 1, wc = wv & 1;
    int c = lane & 15, g = lane >> 4;
    int m0 = blockIdx.x * BM, n0 = blockIdx.y * BN;
    f32x4 acc[4][4] = {};

    for (int kt = 0; kt < DM / BK; ++kt) {
#pragma unroll
        for (int it = 0; it < 4; ++it) {
            int sgi = it * 256 + tid;
            int row = sgi >> 3, blk = sgi & 7;
            int srcoff = kt * BK + ((blk ^ (row & 7)) << 3);
            gload_lds16(A  + (size_t)(m0 + row) * DM + srcoff, &lA[(it*256 + wv*64) * 8]);
            gload_lds16(Bt + (size_t)(n0 + row) * DM + srcoff, &lB[(it*256 + wv*64) * 8]);
        }
        __syncthreads();
#pragma unroll
        for (int ks = 0; ks < 2; ++ks) {
            short8 af[4], bf[4];
#pragma unroll
            for (int mi = 0; mi < 4; ++mi) {
                int row = wr*64 + mi*16 + c;
                af[mi] = *reinterpret_cast<const short8*>(&lA[row*64 + (((ks*4 + g) ^ (row & 7)) << 3)]);
            }
#pragma unroll
            for (int ni = 0; ni < 4; ++ni) {
                int row = wc*64 + ni*16 + c;
                bf[ni] = *reinterpret_cast<const short8*>(&lB[row*64 + (((ks*4 + g) ^ (row & 7)) << 3)]);
            }
#pragma unroll
            for (int mi = 0; mi < 4; ++mi)
#pragma unroll
                for (int ni = 0; ni < 4; ++ni)
                    acc[mi][ni] = __builtin_amdgcn_mfma_f32_16x16x32_bf16(af[mi], bf[ni], acc[mi][ni], 0, 0, 0);
        }
        __syncthreads();
    }

    if (mode == 2) {                     // V^T -> [B,H,Hd,S] bf16 via LDS transpose
        unsigned short* t = lds;         // 128x128 ushorts = 32 KB exactly
#pragma unroll
        for (int mi = 0; mi < 4; ++mi)
#pragma unroll
            for (int ni = 0; ni < 4; ++ni)
#pragma unroll
                for (int r = 0; r < 4; ++r) {
                    int lr = wr*64 + mi*16 + 4*g + r;   // s-local
                    int lc = wc*64 + ni*16 + c;         // col-local
                    t[lc*128 + lr] = f2b(acc[mi][ni][r] + bias[n0 + lc]);
                }
        __syncthreads();
#pragma unroll
        for (int i = 0; i < 8; ++i) {
            int idx = (i*256 + tid) * 8;          // ushort offset in t
            int lc = idx >> 7, lr = idx & 127;
            int gcol = n0 + lc, grow = m0 + lr;
            int b = grow >> 11, s = grow & 2047, h = gcol >> 6, d = gcol & 63;
            *reinterpret_cast<u16x8*>(&outb[((size_t)((b*NH + h) << 6) + d) * SEQ + s]) =
                *reinterpret_cast<u16x8*>(&t[idx]);
        }
    }
}

// ---------------- 256x256 pipelined GEMM (counted vmcnt, fixed FIFO proof) ----
// 512 thr = 8 waves (2M x 4N), per-wave 128x64 out, BK=64, 1 K-tile/iter.
// Per iter: stage FULL next tile (8 loads/wave) -> vmcnt(8) (all current-tile
// loads retired; next-tile loads stay in flight) -> barrier -> 64 MFMA ->
// barrier (WAR protection for next iteration's staging).
__global__ __launch_bounds__(512, 2) void k_gemm256(const unsigned short* __restrict__ A,
                                                    const unsigned short* __restrict__ Bt,
                                                    const float* __restrict__ b0,
                                                    const float* __restrict__ b1,
                                                    unsigned short* __restrict__ oQ,
                                                    unsigned short* __restrict__ oK,
                                                    float* __restrict__ oF,
                                                    int perXcd, int mode) {
    __shared__ unsigned short L[2][2][2][128*64];   // 128 KB
    int tid = threadIdx.x, lane = tid & 63, wid = tid >> 6;
    int wm = wid >> 2, wn = wid & 3;
    int c = lane & 15, g = lane >> 4;

    int bid = blockIdx.x;
    int swz = (bid & 7) * perXcd + (bid >> 3);      // bijective: nwg % 8 == 0
    int mb = swz & 31, nb = swz >> 5;               // M = 8192 -> 32 m-blocks
    int m0 = mb * 256, n0 = nb * 256;

    int idx0 = tid, idx1 = 512 + tid;
    int r0 = idx0 >> 3, k0 = idx0 & 7;
    int r1 = idx1 >> 3, k1 = idx1 & 7;

    auto stageHalf = [&](int buf, int ab, int half, int kt) {
        const unsigned short* src = ab ? Bt : A;
        int base = (ab ? n0 : m0) + half * 128;
        gload_lds16(src + (size_t)(base + r0) * DM + kt*64 + ((k0 ^ (r0 & 7)) << 3),
                    &L[buf][ab][half][idx0 * 8]);
        gload_lds16(src + (size_t)(base + r1) * DM + kt*64 + ((k1 ^ (r1 & 7)) << 3),
                    &L[buf][ab][half][idx1 * 8]);
    };

    f32x4 acc[8][4] = {};
    short8 af[4][2], bf0[2][2], bf1[2][2];

    // prologue: K-tile 0 -> buf 0
    stageHalf(0, 0, 0, 0); stageHalf(0, 1, 0, 0);
    stageHalf(0, 0, 1, 0); stageHalf(0, 1, 1, 0);

#define RDA(BUF, I, MH, KS) (*reinterpret_cast<const short8*>(                         \
        &L[BUF][0][wm][((MH)*64 + (I)*16 + c)*64 +                                     \
                       ((((KS)*4 + g) ^ (((MH)*64 + (I)*16 + c) & 7)) << 3)]))
#define RDB(BUF, J, NHh, KS) (*reinterpret_cast<const short8*>(                        \
        &L[BUF][1][wn>>1][((wn&1)*64 + (NHh)*32 + (J)*16 + c)*64 +                     \
                       ((((KS)*4 + g) ^ (((wn&1)*64 + (NHh)*32 + (J)*16 + c) & 7)) << 3)]))

    for (int it = 0; it < 16; ++it) {
        int cur = it & 1, nxt = cur ^ 1;

        if (it < 15) {
            stageHalf(nxt, 0, 0, it+1); stageHalf(nxt, 1, 0, it+1);
            stageHalf(nxt, 0, 1, it+1); stageHalf(nxt, 1, 1, it+1);
            asm volatile("s_waitcnt vmcnt(8)" ::: "memory");   // tile it fully in LDS
        } else {
            asm volatile("s_waitcnt vmcnt(0)" ::: "memory");
        }
        __builtin_amdgcn_s_barrier();

        // ---- sub-block 0: rows 0-63 x cols 0-31 ----
#pragma unroll
        for (int i = 0; i < 4; ++i) { af[i][0] = RDA(cur, i, 0, 0); af[i][1] = RDA(cur, i, 0, 1); }
#pragma unroll
        for (int j = 0; j < 2; ++j) { bf0[j][0] = RDB(cur, j, 0, 0); bf0[j][1] = RDB(cur, j, 0, 1); }
        __builtin_amdgcn_s_setprio(1);
#pragma unroll
        for (int i = 0; i < 4; ++i)
#pragma unroll
            for (int j = 0; j < 2; ++j) {
                acc[i][j] = __builtin_amdgcn_mfma_f32_16x16x32_bf16(af[i][0], bf0[j][0], acc[i][j], 0, 0, 0);
                acc[i][j] = __builtin_amdgcn_mfma_f32_16x16x32_bf16(af[i][1], bf0[j][1], acc[i][j], 0, 0, 0);
            }
        __builtin_amdgcn_s_setprio(0);

        // ---- sub-block 1: rows 64-127 x cols 0-31 ----
#pragma unroll
        for (int i = 0; i < 4; ++i) { af[i][0] = RDA(cur, i, 1, 0); af[i][1] = RDA(cur, i, 1, 1); }
        __builtin_amdgcn_s_setprio(1);
#pragma unroll
        for (int i = 0; i < 4; ++i)
#pragma unroll
            for (int j = 0; j < 2; ++j) {
                acc[4+i][j] = __builtin_amdgcn_mfma_f32_16x16x32_bf16(af[i][0], bf0[j][0], acc[4+i][j], 0, 0, 0);
                acc[4+i][j] = __builtin_amdgcn_mfma_f32_16x16x32_bf16(af[i][1], bf0[j][1], acc[4+i][j], 0, 0, 0);
            }
        __builtin_amdgcn_s_setprio(0);

        // ---- sub-block 2: rows 64-127 x cols 32-63 ----
#pragma unroll
        for (int j = 0; j < 2; ++j) { bf1[j][0] = RDB(cur, j, 1, 0); bf1[j][1] = RDB(cur, j, 1, 1); }
        __builtin_amdgcn_s_setprio(1);
#pragma unroll
        for (int i = 0; i < 4; ++i)
#pragma unroll
            for (int j = 0; j < 2; ++j) {
                acc[4+i][2+j] = __builtin_amdgcn_mfma_f32_16x16x32_bf16(af[i][0], bf1[j][0], acc[4+i][2+j], 0, 0, 0);
                acc[4+i][2+j] = __builtin_amdgcn_mfma_f32_16x16x32_bf16(af[i][1], bf1[j][1], acc[4+i][2+j], 0, 0, 0);
            }
        __builtin_amdgcn_s_setprio(0);

        // ---- sub-block 3: rows 0-63 x cols 32-63 ----
#pragma unroll
        for (int i = 0; i < 4; ++i) { af[i][0] = RDA(cur, i, 0, 0); af[i][1] = RDA(cur, i, 0, 1); }
        __builtin_amdgcn_s_setprio(1);
#pragma unroll
        for (int i = 0; i < 4; ++i)
#pragma unroll
            for (int j = 0; j < 2; ++j) {
                acc[i][2+j] = __builtin_amdgcn_mfma_f32_16x16x32_bf16(af[i][0], bf1[j][0], acc[i][2+j], 0, 0, 0);
                acc[i][2+j] = __builtin_amdgcn_mfma_f32_16x16x32_bf16(af[i][1], bf1[j][1], acc[i][2+j], 0, 0, 0);
            }
        __builtin_amdgcn_s_setprio(0);

        __builtin_amdgcn_s_barrier();               // WAR: all reads of cur done
    }
#undef RDA
#undef RDB

    if (mode == 0) {                                // Q/K scatter (N=2048)
        int mat = n0 >> 10;                         // block-uniform: 0=Q, 1=K
        const float* bias = mat ? b1 : b0;
        unsigned short* outb = mat ? oK : oQ;
        float sc = mat ? 1.0f : QSCALE;
#pragma unroll
        for (int mf = 0; mf < 8; ++mf)
#pragma unroll
            for (int nf = 0; nf < 4; ++nf)
#pragma unroll
                for (int r = 0; r < 4; ++r) {
                    int gr = m0 + wm*128 + mf*16 + 4*g + r;
                    int gc = n0 + wn*64 + nf*16 + c;
                    int gcm = gc & 1023;
                    float v = (acc[mf][nf][r] + bias[gcm]) * sc;
                    int b = gr >> 11, s = gr & 2047, h = gcm >> 6, d = gcm & 63;
                    outb[(((size_t)(b*NH + h) * SEQ + s) << 6) + d] = f2b(v);
                }
    } else {                                        // O: fp32 + bias
#pragma unroll
        for (int mf = 0; mf < 8; ++mf)
#pragma unroll
            for (int nf = 0; nf < 4; ++nf)
#pragma unroll
                for (int r = 0; r < 4; ++r) {
                    int gr = m0 + wm*128 + mf*16 + 4*g + r;
                    int gc = n0 + wn*64 + nf*16 + c;
                    oF[(size_t)gr * DM + gc] = acc[mf][nf][r] + b0[gc];
                }
    }
}

// ---------------- flash attention (round-8 validated) ----------------
__global__ __launch_bounds__(256) void k_attn(const unsigned short* __restrict__ Q,
                                              const unsigned short* __restrict__ K,
                                              const unsigned short* __restrict__ VT,
                                              unsigned short* __restrict__ AO) {
    __shared__ unsigned short kt[2][64*64], vt[2][64*64];   // 32 KB
    int tid = threadIdx.x, lane = tid & 63, wv = tid >> 6;
    int c = lane & 15, g = lane >> 4;

    int flat = blockIdx.x;
    int nb = (flat & 7) * 256 + (flat >> 3);
    int qb = nb & 31, bh = nb >> 5;

    const unsigned short* Qh = Q  + (size_t)bh * SEQ * HD;
    const unsigned short* Kh = K  + (size_t)bh * SEQ * HD;
    const unsigned short* Vh = VT + (size_t)bh * HD * SEQ;

    int qrow = qb*64 + wv*16 + c;
    short8 qf0 = *reinterpret_cast<const short8*>(&Qh[(size_t)qrow*HD +      g*8]);
    short8 qf1 = *reinterpret_cast<const short8*>(&Qh[(size_t)qrow*HD + 32 + g*8]);

    int row = tid >> 3, blk = tid & 7;
    int xo = (blk ^ (row & 7)) << 3;
    auto srowf = [](int r) {
        return ((r >> 4) & 1)*32 + ((r >> 2) & 3)*8 + ((r >> 5) & 1)*4 + (r & 3);
    };
    const unsigned short* gK0 = Kh + (size_t)srowf(row)      * HD + xo;
    const unsigned short* gK1 = Kh + (size_t)srowf(row + 32) * HD + xo;
    const unsigned short* gV0 = Vh + (size_t)row        * SEQ + xo;
    const unsigned short* gV1 = Vh + (size_t)(row + 32) * SEQ + xo;
    unsigned ldso = wv * 512;

    int swz0 = (g ^ (c & 7)) << 3;
    int swz1 = ((4 + g) ^ (c & 7)) << 3;
    const unsigned short* kb0 = &kt[0][c*64 + swz0];
    const unsigned short* kb1 = &kt[0][c*64 + swz1];
    const unsigned short* vb0 = &vt[0][c*64 + swz0];
    const unsigned short* vb1 = &vt[0][c*64 + swz1];

    float m = -1e30f;
    f32x4 oacc[4] = {}, lacc = {};
    const short ob = (short)0x3F80;                 // bf16 1.0
    const short8 ones = {ob, ob, ob, ob, ob, ob, ob, ob};

#define STAGE(SB) do {                                                        \
        gload_lds16(gK0, &kt[SB][ldso]);                                      \
        gload_lds16(gK1, &kt[SB][2048 + ldso]);                               \
        gload_lds16(gV0, &vt[SB][ldso]);                                      \
        gload_lds16(gV1, &vt[SB][2048 + ldso]);                               \
        gK0 += 64*HD; gK1 += 64*HD; gV0 += 64; gV1 += 64;                     \
    } while (0)

#define TILE(BUFO, PRE) do {                                                  \
        PRE;                                                                  \
        f32x4 sacc[4] = {};                                                   \
        __builtin_amdgcn_s_setprio(1);                                        \
        _Pragma("unroll")                                                     \
        for (int nt = 0; nt < 4; ++nt) {                                      \
            short8 kf0 = *reinterpret_cast<const short8*>(kb0 + (BUFO) + nt*1024); \
            short8 kf1 = *reinterpret_cast<const short8*>(kb1 + (BUFO) + nt*1024); \
            sacc[nt] = __builtin_amdgcn_mfma_f32_16x16x32_bf16(kf0, qf0, sacc[nt], 0, 0, 0); \
            sacc[nt] = __builtin_amdgcn_mfma_f32_16x16x32_bf16(kf1, qf1, sacc[nt], 0, 0, 0); \
        }                                                                     \
        __builtin_amdgcn_s_setprio(0);                                        \
        float x0 = fmaxf(fmaxf(sacc[0][0], sacc[0][1]), sacc[0][2]);          \
        float x1 = fmaxf(fmaxf(sacc[0][3], sacc[1][0]), sacc[1][1]);          \
        float x2 = fmaxf(fmaxf(sacc[1][2], sacc[1][3]), sacc[2][0]);          \
        float x3 = fmaxf(fmaxf(sacc[2][1], sacc[2][2]), sacc[2][3]);          \
        float x4 = fmaxf(fmaxf(sacc[3][0], sacc[3][1]), sacc[3][2]);          \
        float tm = fmaxf(fmaxf(fmaxf(x0, x1), fmaxf(x2, x3)), fmaxf(x4, sacc[3][3])); \
        if (__any(tm > m + 8.0f)) {                                           \
            tm = fmaxf(tm, __shfl_xor(tm, 16, 64));                           \
            tm = fmaxf(tm, __shfl_xor(tm, 32, 64));                           \
            float mn = fmaxf(m, tm);                                          \
            float corr = __builtin_amdgcn_exp2f(m - mn);                      \
            m = mn; lacc *= corr;                                             \
            _Pragma("unroll")                                                 \
            for (int ft = 0; ft < 4; ++ft)                                    \
                _Pragma("unroll")                                             \
                for (int r = 0; r < 4; ++r) oacc[ft][r] *= corr;              \
        }                                                                     \
        _Pragma("unroll")                                                     \
        for (int nt = 0; nt < 4; ++nt)                                        \
            _Pragma("unroll")                                                 \
            for (int r = 0; r < 4; ++r)                                       \
                sacc[nt][r] = __builtin_amdgcn_exp2f(sacc[nt][r] - m);        \
        union { unsigned u[4]; short8 v; } U0, U1;                            \
        U0.u[0] = cvt_pk_bf16(sacc[0][0], sacc[0][1]);                        \
        U0.u[1] = cvt_pk_bf16(sacc[0][2], sacc[0][3]);                        \
        U0.u[2] = cvt_pk_bf16(sacc[2][0], sacc[2][1]);                        \
        U0.u[3] = cvt_pk_bf16(sacc[2][2], sacc[2][3]);                        \
        U1.u[0] = cvt_pk_bf16(sacc[1][0], sacc[1][1]);                        \
        U1.u[1] = cvt_pk_bf16(sacc[1][2], sacc[1][3]);                        \
        U1.u[2] = cvt_pk_bf16(sacc[3][0], sacc[3][1]);                        \
        U1.u[3] = cvt_pk_bf16(sacc[3][2], sacc[3][3]);                        \
        short8 pa0 = U0.v, pa1 = U1.v;                                        \
        __builtin_amdgcn_s_setprio(1);                                        \
        _Pragma("unroll")                                                     \
        for (int ft = 0; ft < 4; ++ft) {                                      \
            short8 vf0 = *reinterpret_cast<const short8*>(vb0 + (BUFO) + ft*1024); \
            short8 vf1 = *reinterpret_cast<const short8*>(vb1 + (BUFO) + ft*1024); \
            oacc[ft] = __builtin_amdgcn_mfma_f32_16x16x32_bf16(vf0, pa0, oacc[ft], 0, 0, 0); \
            oacc[ft] = __builtin_amdgcn_mfma_f32_16x16x32_bf16(vf1, pa1, oacc[ft], 0, 0, 0); \
        }                                                                     \
        lacc = __builtin_amdgcn_mfma_f32_16x16x32_bf16(ones, pa0, lacc, 0, 0, 0); \
        lacc = __builtin_amdgcn_mfma_f32_16x16x32_bf16(ones, pa1, lacc, 0, 0, 0); \
        __builtin_amdgcn_s_setprio(0);                                        \
        __syncthreads();                                                      \
    } while (0)

    STAGE(0);
    __syncthreads();

    for (int tp = 0; tp < 15; ++tp) {
        TILE(0,    STAGE(1));
        TILE(4096, STAGE(0));
    }
    TILE(0,    STAGE(1));
    TILE(4096, (void)0);

#undef STAGE
#undef TILE

    int b = bh >> 4, h = bh & 15;
    float inv = 1.f / lacc[0];
#pragma unroll
    for (int ft = 0; ft < 4; ++ft) {
        u16x4 o4;
#pragma unroll
        for (int r = 0; r < 4; ++r) o4[r] = f2b(oacc[ft][r] * inv);
        *reinterpret_cast<u16x4*>(
            &AO[(size_t)(b*SEQ + qrow) * DM + h*HD + ft*16 + 4*g]) = o4;
    }
}

extern "C" void kernel_launch(void* const* d_in, const int* in_sizes, int n_in,
                              void* d_out, int out_size, void* d_ws, size_t ws_size,
                              hipStream_t stream) {
    const float* x  = (const float*)d_in[0];
    const float* Wq = (const float*)d_in[1];
    const float* bq = (const float*)d_in[2];
    const float* Wk = (const float*)d_in[3];
    const float* bk = (const float*)d_in[4];
    const float* Wv = (const float*)d_in[5];
    const float* bv = (const float*)d_in[6];
    const float* Wo = (const float*)d_in[7];
    const float* bo = (const float*)d_in[8];

    char* ws = (char*)d_ws;
    unsigned short* xb  = (unsigned short*)(ws);                  // 16 MB
    unsigned short* wT  = (unsigned short*)(ws + (16u<<20));      //  8 MB (4 mats)
    unsigned short* Qb  = (unsigned short*)(ws + (24u<<20));      // 16 MB
    unsigned short* Kb  = (unsigned short*)(ws + (40u<<20));      // 16 MB
    unsigned short* VTb = (unsigned short*)(ws + (56u<<20));      // 16 MB
    unsigned short* AOb = (unsigned short*)(ws + (72u<<20));      // 16 MB

    k_cvt_x<<<dim3(MROWS*DM/8/256), 256, 0, stream>>>(x, xb);
    k_cvt_wT<<<dim3(16,16,4), 256, 0, stream>>>(Wq, Wk, Wv, Wo, wT);

    // Q+K fused 256x256 pipelined GEMM: N = 2048 (Wq^T | Wk^T), 256 wgs
    k_gemm256<<<dim3(256), 512, 0, stream>>>(xb, wT, bq, bk, Qb, Kb, nullptr, 32, 0);

    // V via legacy kernel (transpose epilogue)
    k_gemm<<<dim3(MROWS/BM, DM/BN), 256, 0, stream>>>(xb, wT + 2*DM*DM, bv, VTb, nullptr, 2);

    k_attn<<<dim3(SEQ/64 * BATCH*NH), 256, 0, stream>>>(Qb, Kb, VTb, AOb);

    // O projection 256x256 pipelined GEMM: N = 1024, 128 wgs
    k_gemm256<<<dim3(128), 512, 0, stream>>>(AOb, wT + 3*DM*DM, bo, nullptr, nullptr, nullptr,
                                             (float*)d_out, 16, 1);
}

// Round 14
// 198.969 us; speedup vs baseline: 1.0410x; 1.0410x over previous
//
#include <hip/hip_runtime.h>

#define DM 1024
#define NH 16
#define HD 64
#define SEQ 2048
#define BATCH 4
#define MROWS (BATCH*SEQ)   // 8192

typedef short short8 __attribute__((ext_vector_type(8)));
typedef float f32x4 __attribute__((ext_vector_type(4)));
typedef unsigned short u16x8 __attribute__((ext_vector_type(8)));
typedef unsigned short u16x4 __attribute__((ext_vector_type(4)));

__device__ inline unsigned short f2b(float f) {
    union { float f; unsigned u; } v; v.f = f;
    unsigned r = v.u + 0x7fffu + ((v.u >> 16) & 1u);   // RNE
    return (unsigned short)(r >> 16);
}

__device__ inline void gload_lds16(const void* g, void* l) {
    __builtin_amdgcn_global_load_lds(
        (const __attribute__((address_space(1))) void*)g,
        (__attribute__((address_space(3))) void*)l, 16, 0, 0);
}

__device__ inline unsigned cvt_pk_bf16(float lo, float hi) {
    unsigned r;
    asm("v_cvt_pk_bf16_f32 %0, %1, %2" : "=v"(r) : "v"(lo), "v"(hi));
    return r;
}

// ---------------- convert x (fp32 -> bf16) ----------------
__global__ void k_cvt_x(const float* __restrict__ x, unsigned short* __restrict__ xb) {
    long i = ((long)blockIdx.x * 256 + threadIdx.x) * 8;
    float4 a = *reinterpret_cast<const float4*>(x + i);
    float4 b = *reinterpret_cast<const float4*>(x + i + 4);
    u16x8 o;
    o[0]=f2b(a.x); o[1]=f2b(a.y); o[2]=f2b(a.z); o[3]=f2b(a.w);
    o[4]=f2b(b.x); o[5]=f2b(b.y); o[6]=f2b(b.z); o[7]=f2b(b.w);
    *reinterpret_cast<u16x8*>(xb + i) = o;
}

// ---------------- convert + transpose W (fp32 [k][n] -> bf16 [n][k]) ----------------
__global__ void k_cvt_wT(const float* W0, const float* W1, const float* W2, const float* W3,
                         unsigned short* __restrict__ out) {
    const float* Ws[4] = {W0, W1, W2, W3};
    const float* W = Ws[blockIdx.z];
    unsigned short* o = out + (size_t)blockIdx.z * DM * DM;
    __shared__ float t[64][65];
    int tx = threadIdx.x & 15, ty = threadIdx.x >> 4;
    int nb = blockIdx.x * 64, kb = blockIdx.y * 64;
#pragma unroll
    for (int i = 0; i < 4; ++i) {
        int r = ty + 16 * i;
        float4 v = *reinterpret_cast<const float4*>(W + (size_t)(kb + r) * DM + nb + tx * 4);
        t[r][tx*4+0] = v.x; t[r][tx*4+1] = v.y; t[r][tx*4+2] = v.z; t[r][tx*4+3] = v.w;
    }
    __syncthreads();
#pragma unroll
    for (int i = 0; i < 4; ++i) {
        int r = ty + 16 * i;                  // n-local
        u16x4 pv;
#pragma unroll
        for (int j = 0; j < 4; ++j) pv[j] = f2b(t[tx*4+j][r]);
        *reinterpret_cast<u16x4*>(o + (size_t)(nb + r) * DM + kb + tx * 4) = pv;
    }
}

#define BM 128
#define BN 128
#define BK 64
#define QSCALE 0.1803368801f   // 0.125 * log2(e)

// ---------------- legacy 128x128 GEMM (used for V only: mode 2) ----------------
__global__ __launch_bounds__(256) void k_gemm(const unsigned short* __restrict__ A,
                                              const unsigned short* __restrict__ Bt,
                                              const float* __restrict__ bias,
                                              unsigned short* __restrict__ outb,
                                              float* __restrict__ outf, int mode) {
    __shared__ unsigned short lds[BM*BK + BN*BK];   // 32 KB
    unsigned short* lA = lds;
    unsigned short* lB = lds + BM*BK;
    int tid = threadIdx.x, lane = tid & 63, wv = tid >> 6;
    int wr = wv >> 1, wc = wv & 1;
    int c = lane & 15, g = lane >> 4;
    int m0 = blockIdx.x * BM, n0 = blockIdx.y * BN;
    f32x4 acc[4][4] = {};

    for (int kt = 0; kt < DM / BK; ++kt) {
#pragma unroll
        for (int it = 0; it < 4; ++it) {
            int sgi = it * 256 + tid;
            int row = sgi >> 3, blk = sgi & 7;
            int srcoff = kt * BK + ((blk ^ (row & 7)) << 3);
            gload_lds16(A  + (size_t)(m0 + row) * DM + srcoff, &lA[(it*256 + wv*64) * 8]);
            gload_lds16(Bt + (size_t)(n0 + row) * DM + srcoff, &lB[(it*256 + wv*64) * 8]);
        }
        __syncthreads();
#pragma unroll
        for (int ks = 0; ks < 2; ++ks) {
            short8 af[4], bf[4];
#pragma unroll
            for (int mi = 0; mi < 4; ++mi) {
                int row = wr*64 + mi*16 + c;
                af[mi] = *reinterpret_cast<const short8*>(&lA[row*64 + (((ks*4 + g) ^ (row & 7)) << 3)]);
            }
#pragma unroll
            for (int ni = 0; ni < 4; ++ni) {
                int row = wc*64 + ni*16 + c;
                bf[ni] = *reinterpret_cast<const short8*>(&lB[row*64 + (((ks*4 + g) ^ (row & 7)) << 3)]);
            }
#pragma unroll
            for (int mi = 0; mi < 4; ++mi)
#pragma unroll
                for (int ni = 0; ni < 4; ++ni)
                    acc[mi][ni] = __builtin_amdgcn_mfma_f32_16x16x32_bf16(af[mi], bf[ni], acc[mi][ni], 0, 0, 0);
        }
        __syncthreads();
    }

    if (mode == 2) {                     // V^T -> [B,H,Hd,S] bf16 via LDS transpose
        unsigned short* t = lds;         // 128x128 ushorts = 32 KB exactly
#pragma unroll
        for (int mi = 0; mi < 4; ++mi)
#pragma unroll
            for (int ni = 0; ni < 4; ++ni)
#pragma unroll
                for (int r = 0; r < 4; ++r) {
                    int lr = wr*64 + mi*16 + 4*g + r;   // s-local
                    int lc = wc*64 + ni*16 + c;         // col-local
                    t[lc*128 + lr] = f2b(acc[mi][ni][r] + bias[n0 + lc]);
                }
        __syncthreads();
#pragma unroll
        for (int i = 0; i < 8; ++i) {
            int idx = (i*256 + tid) * 8;          // ushort offset in t
            int lc = idx >> 7, lr = idx & 127;
            int gcol = n0 + lc, grow = m0 + lr;
            int b = grow >> 11, s = grow & 2047, h = gcol >> 6, d = gcol & 63;
            *reinterpret_cast<u16x8*>(&outb[((size_t)((b*NH + h) << 6) + d) * SEQ + s]) =
                *reinterpret_cast<u16x8*>(&t[idx]);
        }
    }
}

// ---------------- 256x256 pipelined GEMM (QK; validated round 12) ----------------
__global__ __launch_bounds__(512, 2) void k_gemm256(const unsigned short* __restrict__ A,
                                                    const unsigned short* __restrict__ Bt,
                                                    const float* __restrict__ b0,
                                                    const float* __restrict__ b1,
                                                    unsigned short* __restrict__ oQ,
                                                    unsigned short* __restrict__ oK,
                                                    float* __restrict__ oF,
                                                    int perXcd, int mode) {
    __shared__ unsigned short L[2][2][2][128*64];   // 128 KB
    int tid = threadIdx.x, lane = tid & 63, wid = tid >> 6;
    int wm = wid >> 2, wn = wid & 3;
    int c = lane & 15, g = lane >> 4;

    int bid = blockIdx.x;
    int swz = (bid & 7) * perXcd + (bid >> 3);      // bijective: nwg % 8 == 0
    int mb = swz & 31, nb = swz >> 5;               // M = 8192 -> 32 m-blocks
    int m0 = mb * 256, n0 = nb * 256;

    int idx0 = tid, idx1 = 512 + tid;
    int r0 = idx0 >> 3, k0 = idx0 & 7;
    int r1 = idx1 >> 3, k1 = idx1 & 7;

    auto stageHalf = [&](int buf, int ab, int half, int kt) {
        const unsigned short* src = ab ? Bt : A;
        int base = (ab ? n0 : m0) + half * 128;
        gload_lds16(src + (size_t)(base + r0) * DM + kt*64 + ((k0 ^ (r0 & 7)) << 3),
                    &L[buf][ab][half][idx0 * 8]);
        gload_lds16(src + (size_t)(base + r1) * DM + kt*64 + ((k1 ^ (r1 & 7)) << 3),
                    &L[buf][ab][half][idx1 * 8]);
    };

    f32x4 acc[8][4] = {};
    short8 af[4][2], bf0[2][2], bf1[2][2];

    stageHalf(0, 0, 0, 0); stageHalf(0, 1, 0, 0);
    stageHalf(0, 0, 1, 0); stageHalf(0, 1, 1, 0);

#define RDA(BUF, I, MH, KS) (*reinterpret_cast<const short8*>(                         \
        &L[BUF][0][wm][((MH)*64 + (I)*16 + c)*64 +                                     \
                       ((((KS)*4 + g) ^ (((MH)*64 + (I)*16 + c) & 7)) << 3)]))
#define RDB(BUF, J, NHh, KS) (*reinterpret_cast<const short8*>(                        \
        &L[BUF][1][wn>>1][((wn&1)*64 + (NHh)*32 + (J)*16 + c)*64 +                     \
                       ((((KS)*4 + g) ^ (((wn&1)*64 + (NHh)*32 + (J)*16 + c) & 7)) << 3)]))

    for (int it = 0; it < 16; ++it) {
        int cur = it & 1, nxt = cur ^ 1;

        if (it < 15) {
            stageHalf(nxt, 0, 0, it+1); stageHalf(nxt, 1, 0, it+1);
            stageHalf(nxt, 0, 1, it+1); stageHalf(nxt, 1, 1, it+1);
            asm volatile("s_waitcnt vmcnt(8)" ::: "memory");
        } else {
            asm volatile("s_waitcnt vmcnt(0)" ::: "memory");
        }
        __builtin_amdgcn_s_barrier();

#pragma unroll
        for (int i = 0; i < 4; ++i) { af[i][0] = RDA(cur, i, 0, 0); af[i][1] = RDA(cur, i, 0, 1); }
#pragma unroll
        for (int j = 0; j < 2; ++j) { bf0[j][0] = RDB(cur, j, 0, 0); bf0[j][1] = RDB(cur, j, 0, 1); }
        __builtin_amdgcn_s_setprio(1);
#pragma unroll
        for (int i = 0; i < 4; ++i)
#pragma unroll
            for (int j = 0; j < 2; ++j) {
                acc[i][j] = __builtin_amdgcn_mfma_f32_16x16x32_bf16(af[i][0], bf0[j][0], acc[i][j], 0, 0, 0);
                acc[i][j] = __builtin_amdgcn_mfma_f32_16x16x32_bf16(af[i][1], bf0[j][1], acc[i][j], 0, 0, 0);
            }
        __builtin_amdgcn_s_setprio(0);

#pragma unroll
        for (int i = 0; i < 4; ++i) { af[i][0] = RDA(cur, i, 1, 0); af[i][1] = RDA(cur, i, 1, 1); }
        __builtin_amdgcn_s_setprio(1);
#pragma unroll
        for (int i = 0; i < 4; ++i)
#pragma unroll
            for (int j = 0; j < 2; ++j) {
                acc[4+i][j] = __builtin_amdgcn_mfma_f32_16x16x32_bf16(af[i][0], bf0[j][0], acc[4+i][j], 0, 0, 0);
                acc[4+i][j] = __builtin_amdgcn_mfma_f32_16x16x32_bf16(af[i][1], bf0[j][1], acc[4+i][j], 0, 0, 0);
            }
        __builtin_amdgcn_s_setprio(0);

#pragma unroll
        for (int j = 0; j < 2; ++j) { bf1[j][0] = RDB(cur, j, 1, 0); bf1[j][1] = RDB(cur, j, 1, 1); }
        __builtin_amdgcn_s_setprio(1);
#pragma unroll
        for (int i = 0; i < 4; ++i)
#pragma unroll
            for (int j = 0; j < 2; ++j) {
                acc[4+i][2+j] = __builtin_amdgcn_mfma_f32_16x16x32_bf16(af[i][0], bf1[j][0], acc[4+i][2+j], 0, 0, 0);
                acc[4+i][2+j] = __builtin_amdgcn_mfma_f32_16x16x32_bf16(af[i][1], bf1[j][1], acc[4+i][2+j], 0, 0, 0);
            }
        __builtin_amdgcn_s_setprio(0);

#pragma unroll
        for (int i = 0; i < 4; ++i) { af[i][0] = RDA(cur, i, 0, 0); af[i][1] = RDA(cur, i, 0, 1); }
        __builtin_amdgcn_s_setprio(1);
#pragma unroll
        for (int i = 0; i < 4; ++i)
#pragma unroll
            for (int j = 0; j < 2; ++j) {
                acc[i][2+j] = __builtin_amdgcn_mfma_f32_16x16x32_bf16(af[i][0], bf1[j][0], acc[i][2+j], 0, 0, 0);
                acc[i][2+j] = __builtin_amdgcn_mfma_f32_16x16x32_bf16(af[i][1], bf1[j][1], acc[i][2+j], 0, 0, 0);
            }
        __builtin_amdgcn_s_setprio(0);

        __builtin_amdgcn_s_barrier();
    }
#undef RDA
#undef RDB

    if (mode == 0) {                                // Q/K scatter (N=2048)
        int mat = n0 >> 10;
        const float* bias = mat ? b1 : b0;
        unsigned short* outb = mat ? oK : oQ;
        float sc = mat ? 1.0f : QSCALE;
#pragma unroll
        for (int mf = 0; mf < 8; ++mf)
#pragma unroll
            for (int nf = 0; nf < 4; ++nf)
#pragma unroll
                for (int r = 0; r < 4; ++r) {
                    int gr = m0 + wm*128 + mf*16 + 4*g + r;
                    int gc = n0 + wn*64 + nf*16 + c;
                    int gcm = gc & 1023;
                    float v = (acc[mf][nf][r] + bias[gcm]) * sc;
                    int b = gr >> 11, s = gr & 2047, h = gcm >> 6, d = gcm & 63;
                    outb[(((size_t)(b*NH + h) * SEQ + s) << 6) + d] = f2b(v);
                }
    } else {
#pragma unroll
        for (int mf = 0; mf < 8; ++mf)
#pragma unroll
            for (int nf = 0; nf < 4; ++nf)
#pragma unroll
                for (int r = 0; r < 4; ++r) {
                    int gr = m0 + wm*128 + mf*16 + 4*g + r;
                    int gc = n0 + wn*64 + nf*16 + c;
                    oF[(size_t)gr * DM + gc] = acc[mf][nf][r] + b0[gc];
                }
    }
}

// ---------------- 256x128 pipelined GEMM for O (full-chip: 32x8 = 256 wgs) ----
// Counted-vmcnt skeleton; 6 loads/wave/tile (A: 2 halves, B: 1), vmcnt(6).
// Wave (wm,wn): owns rows {half*128 + wm*64 + [0,64)} x cols wn*32+[0,32).
__global__ __launch_bounds__(512, 2) void k_gemm_o256(const unsigned short* __restrict__ A,
                                                      const unsigned short* __restrict__ Bt,
                                                      const float* __restrict__ bias,
                                                      float* __restrict__ oF) {
    __shared__ unsigned short L[2][3][128*64];      // 96 KB: [buf][Ah0,Ah1,B]
    int tid = threadIdx.x, lane = tid & 63, wid = tid >> 6;
    int wm = wid >> 2, wn = wid & 3;
    int c = lane & 15, g = lane >> 4;

    int bid = blockIdx.x;
    int swz = (bid & 7) * 32 + (bid >> 3);          // 256 wgs, bijective
    int mb = swz & 31, nb = swz >> 5;               // 32 m x 8 n
    int m0 = mb * 256, n0 = nb * 128;

    int idx0 = tid, idx1 = 512 + tid;
    int r0 = idx0 >> 3, k0 = idx0 & 7;
    int r1 = idx1 >> 3, k1 = idx1 & 7;

    auto stageA = [&](int buf, int half, int kt) {
        int base = m0 + half * 128;
        gload_lds16(A + (size_t)(base + r0) * DM + kt*64 + ((k0 ^ (r0 & 7)) << 3),
                    &L[buf][half][idx0 * 8]);
        gload_lds16(A + (size_t)(base + r1) * DM + kt*64 + ((k1 ^ (r1 & 7)) << 3),
                    &L[buf][half][idx1 * 8]);
    };
    auto stageB = [&](int buf, int kt) {
        gload_lds16(Bt + (size_t)(n0 + r0) * DM + kt*64 + ((k0 ^ (r0 & 7)) << 3),
                    &L[buf][2][idx0 * 8]);
        gload_lds16(Bt + (size_t)(n0 + r1) * DM + kt*64 + ((k1 ^ (r1 & 7)) << 3),
                    &L[buf][2][idx1 * 8]);
    };

    f32x4 acc[8][2] = {};
    short8 af[4][2], bf[2][2];

    stageA(0, 0, 0); stageA(0, 1, 0); stageB(0, 0);

    // FIX (round 13 bug): row includes the wave's 64-row sub-half: wm*64 + i*16 + c
#define RDA(BUF, I, MH, KS) (*reinterpret_cast<const short8*>(                         \
        &L[BUF][MH][(wm*64 + (I)*16 + c)*64 +                                          \
                    ((((KS)*4 + g) ^ ((wm*64 + (I)*16 + c) & 7)) << 3)]))
#define RDB(BUF, J, KS) (*reinterpret_cast<const short8*>(                             \
        &L[BUF][2][(wn*32 + (J)*16 + c)*64 +                                           \
                   ((((KS)*4 + g) ^ ((wn*32 + (J)*16 + c) & 7)) << 3)]))

    for (int it = 0; it < 16; ++it) {
        int cur = it & 1, nxt = cur ^ 1;

        if (it < 15) {
            stageA(nxt, 0, it+1); stageA(nxt, 1, it+1); stageB(nxt, it+1);
            asm volatile("s_waitcnt vmcnt(6)" ::: "memory");   // tile it fully landed
        } else {
            asm volatile("s_waitcnt vmcnt(0)" ::: "memory");
        }
        __builtin_amdgcn_s_barrier();

        // half 0 (rows m0 + wm*64 + ...)
#pragma unroll
        for (int i = 0; i < 4; ++i) { af[i][0] = RDA(cur, i, 0, 0); af[i][1] = RDA(cur, i, 0, 1); }
#pragma unroll
        for (int j = 0; j < 2; ++j) { bf[j][0] = RDB(cur, j, 0); bf[j][1] = RDB(cur, j, 1); }
        __builtin_amdgcn_s_setprio(1);
#pragma unroll
        for (int i = 0; i < 4; ++i)
#pragma unroll
            for (int j = 0; j < 2; ++j) {
                acc[i][j] = __builtin_amdgcn_mfma_f32_16x16x32_bf16(af[i][0], bf[j][0], acc[i][j], 0, 0, 0);
                acc[i][j] = __builtin_amdgcn_mfma_f32_16x16x32_bf16(af[i][1], bf[j][1], acc[i][j], 0, 0, 0);
            }
        __builtin_amdgcn_s_setprio(0);

        // half 1 (rows m0 + 128 + wm*64 + ...)
#pragma unroll
        for (int i = 0; i < 4; ++i) { af[i][0] = RDA(cur, i, 1, 0); af[i][1] = RDA(cur, i, 1, 1); }
        __builtin_amdgcn_s_setprio(1);
#pragma unroll
        for (int i = 0; i < 4; ++i)
#pragma unroll
            for (int j = 0; j < 2; ++j) {
                acc[4+i][j] = __builtin_amdgcn_mfma_f32_16x16x32_bf16(af[i][0], bf[j][0], acc[4+i][j], 0, 0, 0);
                acc[4+i][j] = __builtin_amdgcn_mfma_f32_16x16x32_bf16(af[i][1], bf[j][1], acc[4+i][j], 0, 0, 0);
            }
        __builtin_amdgcn_s_setprio(0);

        __builtin_amdgcn_s_barrier();
    }
#undef RDA
#undef RDB

#pragma unroll
    for (int mf = 0; mf < 8; ++mf)
#pragma unroll
        for (int nf = 0; nf < 2; ++nf)
#pragma unroll
            for (int r = 0; r < 4; ++r) {
                int half = mf >> 2, i = mf & 3;
                int gr = m0 + half*128 + wm*64 + i*16 + 4*g + r;
                int gc = n0 + wn*32 + nf*16 + c;
                oF[(size_t)gr * DM + gc] = acc[mf][nf][r] + bias[gc];
            }
}

// ---------------- flash attention (round-8 validated) ----------------
__global__ __launch_bounds__(256) void k_attn(const unsigned short* __restrict__ Q,
                                              const unsigned short* __restrict__ K,
                                              const unsigned short* __restrict__ VT,
                                              unsigned short* __restrict__ AO) {
    __shared__ unsigned short kt[2][64*64], vt[2][64*64];   // 32 KB
    int tid = threadIdx.x, lane = tid & 63, wv = tid >> 6;
    int c = lane & 15, g = lane >> 4;

    int flat = blockIdx.x;
    int nb = (flat & 7) * 256 + (flat >> 3);
    int qb = nb & 31, bh = nb >> 5;

    const unsigned short* Qh = Q  + (size_t)bh * SEQ * HD;
    const unsigned short* Kh = K  + (size_t)bh * SEQ * HD;
    const unsigned short* Vh = VT + (size_t)bh * HD * SEQ;

    int qrow = qb*64 + wv*16 + c;
    short8 qf0 = *reinterpret_cast<const short8*>(&Qh[(size_t)qrow*HD +      g*8]);
    short8 qf1 = *reinterpret_cast<const short8*>(&Qh[(size_t)qrow*HD + 32 + g*8]);

    int row = tid >> 3, blk = tid & 7;
    int xo = (blk ^ (row & 7)) << 3;
    auto srowf = [](int r) {
        return ((r >> 4) & 1)*32 + ((r >> 2) & 3)*8 + ((r >> 5) & 1)*4 + (r & 3);
    };
    const unsigned short* gK0 = Kh + (size_t)srowf(row)      * HD + xo;
    const unsigned short* gK1 = Kh + (size_t)srowf(row + 32) * HD + xo;
    const unsigned short* gV0 = Vh + (size_t)row        * SEQ + xo;
    const unsigned short* gV1 = Vh + (size_t)(row + 32) * SEQ + xo;
    unsigned ldso = wv * 512;

    int swz0 = (g ^ (c & 7)) << 3;
    int swz1 = ((4 + g) ^ (c & 7)) << 3;
    const unsigned short* kb0 = &kt[0][c*64 + swz0];
    const unsigned short* kb1 = &kt[0][c*64 + swz1];
    const unsigned short* vb0 = &vt[0][c*64 + swz0];
    const unsigned short* vb1 = &vt[0][c*64 + swz1];

    float m = -1e30f;
    f32x4 oacc[4] = {}, lacc = {};
    const short ob = (short)0x3F80;                 // bf16 1.0
    const short8 ones = {ob, ob, ob, ob, ob, ob, ob, ob};

#define STAGE(SB) do {                                                        \
        gload_lds16(gK0, &kt[SB][ldso]);                                      \
        gload_lds16(gK1, &kt[SB][2048 + ldso]);                               \
        gload_lds16(gV0, &vt[SB][ldso]);                                      \
        gload_lds16(gV1, &vt[SB][2048 + ldso]);                               \
        gK0 += 64*HD; gK1 += 64*HD; gV0 += 64; gV1 += 64;                     \
    } while (0)

#define TILE(BUFO, PRE) do {                                                  \
        PRE;                                                                  \
        f32x4 sacc[4] = {};                                                   \
        __builtin_amdgcn_s_setprio(1);                                        \
        _Pragma("unroll")                                                     \
        for (int nt = 0; nt < 4; ++nt) {                                      \
            short8 kf0 = *reinterpret_cast<const short8*>(kb0 + (BUFO) + nt*1024); \
            short8 kf1 = *reinterpret_cast<const short8*>(kb1 + (BUFO) + nt*1024); \
            sacc[nt] = __builtin_amdgcn_mfma_f32_16x16x32_bf16(kf0, qf0, sacc[nt], 0, 0, 0); \
            sacc[nt] = __builtin_amdgcn_mfma_f32_16x16x32_bf16(kf1, qf1, sacc[nt], 0, 0, 0); \
        }                                                                     \
        __builtin_amdgcn_s_setprio(0);                                        \
        float x0 = fmaxf(fmaxf(sacc[0][0], sacc[0][1]), sacc[0][2]);          \
        float x1 = fmaxf(fmaxf(sacc[0][3], sacc[1][0]), sacc[1][1]);          \
        float x2 = fmaxf(fmaxf(sacc[1][2], sacc[1][3]), sacc[2][0]);          \
        float x3 = fmaxf(fmaxf(sacc[2][1], sacc[2][2]), sacc[2][3]);          \
        float x4 = fmaxf(fmaxf(sacc[3][0], sacc[3][1]), sacc[3][2]);          \
        float tm = fmaxf(fmaxf(fmaxf(x0, x1), fmaxf(x2, x3)), fmaxf(x4, sacc[3][3])); \
        if (__any(tm > m + 8.0f)) {                                           \
            tm = fmaxf(tm, __shfl_xor(tm, 16, 64));                           \
            tm = fmaxf(tm, __shfl_xor(tm, 32, 64));                           \
            float mn = fmaxf(m, tm);                                          \
            float corr = __builtin_amdgcn_exp2f(m - mn);                      \
            m = mn; lacc *= corr;                                             \
            _Pragma("unroll")                                                 \
            for (int ft = 0; ft < 4; ++ft)                                    \
                _Pragma("unroll")                                             \
                for (int r = 0; r < 4; ++r) oacc[ft][r] *= corr;              \
        }                                                                     \
        _Pragma("unroll")                                                     \
        for (int nt = 0; nt < 4; ++nt)                                        \
            _Pragma("unroll")                                                 \
            for (int r = 0; r < 4; ++r)                                       \
                sacc[nt][r] = __builtin_amdgcn_exp2f(sacc[nt][r] - m);        \
        union { unsigned u[4]; short8 v; } U0, U1;                            \
        U0.u[0] = cvt_pk_bf16(sacc[0][0], sacc[0][1]);                        \
        U0.u[1] = cvt_pk_bf16(sacc[0][2], sacc[0][3]);                        \
        U0.u[2] = cvt_pk_bf16(sacc[2][0], sacc[2][1]);                        \
        U0.u[3] = cvt_pk_bf16(sacc[2][2], sacc[2][3]);                        \
        U1.u[0] = cvt_pk_bf16(sacc[1][0], sacc[1][1]);                        \
        U1.u[1] = cvt_pk_bf16(sacc[1][2], sacc[1][3]);                        \
        U1.u[2] = cvt_pk_bf16(sacc[3][0], sacc[3][1]);                        \
        U1.u[3] = cvt_pk_bf16(sacc[3][2], sacc[3][3]);                        \
        short8 pa0 = U0.v, pa1 = U1.v;                                        \
        __builtin_amdgcn_s_setprio(1);                                        \
        _Pragma("unroll")                                                     \
        for (int ft = 0; ft < 4; ++ft) {                                      \
            short8 vf0 = *reinterpret_cast<const short8*>(vb0 + (BUFO) + ft*1024); \
            short8 vf1 = *reinterpret_cast<const short8*>(vb1 + (BUFO) + ft*1024); \
            oacc[ft] = __builtin_amdgcn_mfma_f32_16x16x32_bf16(vf0, pa0, oacc[ft], 0, 0, 0); \
            oacc[ft] = __builtin_amdgcn_mfma_f32_16x16x32_bf16(vf1, pa1, oacc[ft], 0, 0, 0); \
        }                                                                     \
        lacc = __builtin_amdgcn_mfma_f32_16x16x32_bf16(ones, pa0, lacc, 0, 0, 0); \
        lacc = __builtin_amdgcn_mfma_f32_16x16x32_bf16(ones, pa1, lacc, 0, 0, 0); \
        __builtin_amdgcn_s_setprio(0);                                        \
        __syncthreads();                                                      \
    } while (0)

    STAGE(0);
    __syncthreads();

    for (int tp = 0; tp < 15; ++tp) {
        TILE(0,    STAGE(1));
        TILE(4096, STAGE(0));
    }
    TILE(0,    STAGE(1));
    TILE(4096, (void)0);

#undef STAGE
#undef TILE

    int b = bh >> 4, h = bh & 15;
    float inv = 1.f / lacc[0];
#pragma unroll
    for (int ft = 0; ft < 4; ++ft) {
        u16x4 o4;
#pragma unroll
        for (int r = 0; r < 4; ++r) o4[r] = f2b(oacc[ft][r] * inv);
        *reinterpret_cast<u16x4*>(
            &AO[(size_t)(b*SEQ + qrow) * DM + h*HD + ft*16 + 4*g]) = o4;
    }
}

extern "C" void kernel_launch(void* const* d_in, const int* in_sizes, int n_in,
                              void* d_out, int out_size, void* d_ws, size_t ws_size,
                              hipStream_t stream) {
    const float* x  = (const float*)d_in[0];
    const float* Wq = (const float*)d_in[1];
    const float* bq = (const float*)d_in[2];
    const float* Wk = (const float*)d_in[3];
    const float* bk = (const float*)d_in[4];
    const float* Wv = (const float*)d_in[5];
    const float* bv = (const float*)d_in[6];
    const float* Wo = (const float*)d_in[7];
    const float* bo = (const float*)d_in[8];

    char* ws = (char*)d_ws;
    unsigned short* xb  = (unsigned short*)(ws);                  // 16 MB
    unsigned short* wT  = (unsigned short*)(ws + (16u<<20));      //  8 MB (4 mats)
    unsigned short* Qb  = (unsigned short*)(ws + (24u<<20));      // 16 MB
    unsigned short* Kb  = (unsigned short*)(ws + (40u<<20));      // 16 MB
    unsigned short* VTb = (unsigned short*)(ws + (56u<<20));      // 16 MB
    unsigned short* AOb = (unsigned short*)(ws + (72u<<20));      // 16 MB

    k_cvt_x<<<dim3(MROWS*DM/8/256), 256, 0, stream>>>(x, xb);
    k_cvt_wT<<<dim3(16,16,4), 256, 0, stream>>>(Wq, Wk, Wv, Wo, wT);

    // Q+K fused 256x256 pipelined GEMM: N = 2048 (Wq^T | Wk^T), 256 wgs
    k_gemm256<<<dim3(256), 512, 0, stream>>>(xb, wT, bq, bk, Qb, Kb, nullptr, 32, 0);

    // V via legacy kernel (transpose epilogue)
    k_gemm<<<dim3(MROWS/BM, DM/BN), 256, 0, stream>>>(xb, wT + 2*DM*DM, bv, VTb, nullptr, 2);

    k_attn<<<dim3(SEQ/64 * BATCH*NH), 256, 0, stream>>>(Qb, Kb, VTb, AOb);

    // O projection 256x128 pipelined GEMM: full chip, 256 wgs
    k_gemm_o256<<<dim3(256), 512, 0, stream>>>(AOb, wT + 3*DM*DM, bo, (float*)d_out);
}